// Round 1
// baseline (476.323 us; speedup 1.0000x reference)
//
#include <hip/hip_runtime.h>

#define NPTS 262144
#define KVOL 27
#define NPAIRS 65536
#define CH 64

typedef __attribute__((ext_vector_type(8))) short bf16x8;
typedef __attribute__((ext_vector_type(4))) float f32x4;

__device__ inline unsigned short f2bf(float x){
  unsigned int u = __float_as_uint(x);
  u += 0x7FFFu + ((u >> 16) & 1u);   // round-to-nearest-even
  return (unsigned short)(u >> 16);
}

// ---- feat fp32 -> bf16 (vectorized float4 -> ushort4) ----
__global__ void k_conv_feat(const float* __restrict__ f, unsigned short* __restrict__ o){
  int i = blockIdx.x * blockDim.x + threadIdx.x;   // over NPTS*CH/4
  float4 v = ((const float4*)f)[i];
  ushort4 r;
  r.x = f2bf(v.x); r.y = f2bf(v.y); r.z = f2bf(v.z); r.w = f2bf(v.w);
  ((ushort4*)o)[i] = r;
}

// ---- weight fp32 [K][Cin][Cout] -> bf16 packed as [k][kb][col][j], kb=k/8, j=k%8 ----
// so a B-fragment (8 contiguous bf16 = 16B) is one vector load.
__global__ void k_pack_w(const float* __restrict__ w, unsigned short* __restrict__ o){
  int i = blockIdx.x * blockDim.x + threadIdx.x;
  if (i >= KVOL*CH*CH) return;
  int j = i & 7, col = (i >> 3) & 63, kb = (i >> 9) & 7, k = i >> 12;
  o[i] = f2bf(w[(k*CH + kb*8 + j)*CH + col]);
}

// ---- sparse conv: block = 4 waves, each wave = 16 pairs of one kernel offset ----
// A-frag: row=lane&15 (pair), k=(lane>>4)*8+j  -> 16B global gather per lane
// B-frag: col=lane&15, k=(lane>>4)*8+j         -> 16B load from wpack
// D:      col=lane&15, row=(lane>>4)*4+reg
__global__ __launch_bounds__(256) void k_conv(
    const unsigned short* __restrict__ featb, const unsigned short* __restrict__ wpack,
    const int* __restrict__ kmap, float* __restrict__ out)
{
  int bid = blockIdx.x;
  int k = bid >> 10;           // 1024 tiles of 64 pairs per offset k
  int tile = bid & 1023;
  int tid = threadIdx.x;
  int wv = tid >> 6;
  int l = tid & 63;
  int lg = l >> 4;             // lane group 0..3
  int li = l & 15;

  // B fragments [col-tile][k-half], identical across waves (L2-cached)
  const bf16x8* wp = (const bf16x8*)wpack;   // vec index = (k*8 + kb)*64 + col
  bf16x8 B[4][2];
  #pragma unroll
  for (int t = 0; t < 4; t++)
    #pragma unroll
    for (int kk = 0; kk < 2; kk++){
      int kb = kk*4 + lg;
      B[t][kk] = wp[(k*8 + kb)*64 + t*16 + li];
    }

  int pair = tile*64 + wv*16 + li;
  const int2* km = (const int2*)kmap;        // [K][NPAIRS][2]
  int2 io = km[k*NPAIRS + pair];
  int in = io.x, oidx = io.y;

  const bf16x8* fb = (const bf16x8*)featb;   // row stride = 8 vecs (64 bf16)
  bf16x8 A0 = fb[in*8 + lg];                 // k-half 0: k = lg*8 + j
  bf16x8 A1 = fb[in*8 + 4 + lg];             // k-half 1: k = 32 + lg*8 + j

  f32x4 acc[4];
  #pragma unroll
  for (int t = 0; t < 4; t++){
    acc[t] = (f32x4)(0.0f);
    acc[t] = __builtin_amdgcn_mfma_f32_16x16x32_bf16(A0, B[t][0], acc[t], 0, 0, 0);
    acc[t] = __builtin_amdgcn_mfma_f32_16x16x32_bf16(A1, B[t][1], acc[t], 0, 0, 0);
  }

  // scatter-add: lane holds D rows lg*4+reg (pairs wv*16 + lg*4+reg), cols t*16+li
  int orow[4];
  #pragma unroll
  for (int r = 0; r < 4; r++) orow[r] = __shfl(oidx, lg*4 + r, 64);
  #pragma unroll
  for (int r = 0; r < 4; r++){
    float* base = out + (long long)orow[r]*CH;
    #pragma unroll
    for (int t = 0; t < 4; t++)
      atomicAdd(base + t*16 + li, acc[t][r]);
  }
}

// ---- per-channel sum & sumsq ----
__global__ void k_reduce(const float* __restrict__ out, float* __restrict__ stats){
  int tid = threadIdx.x;
  int ch = tid & 63;
  int rg = tid >> 6;   // 0..3
  float s = 0.f, s2 = 0.f;
  for (int row = blockIdx.x*4 + rg; row < NPTS; row += gridDim.x*4){
    float v = out[(long long)row*CH + ch];
    s += v; s2 += v*v;
  }
  __shared__ float ls[2][256];
  ls[0][tid] = s; ls[1][tid] = s2;
  __syncthreads();
  if (tid < 64){
    s  = ls[0][tid] + ls[0][tid+64] + ls[0][tid+128] + ls[0][tid+192];
    s2 = ls[1][tid] + ls[1][tid+64] + ls[1][tid+128] + ls[1][tid+192];
    atomicAdd(&stats[tid], s);
    atomicAdd(&stats[64+tid], s2);
  }
}

// ---- BN (training-mode batch stats, biased var) + ReLU, in place ----
__global__ void k_bn(float* __restrict__ out, const float* __restrict__ stats,
                     const float* __restrict__ g, const float* __restrict__ b){
  int i = blockIdx.x * blockDim.x + threadIdx.x;  // over NPTS*CH/4
  float4 v = ((const float4*)out)[i];
  int c0 = (i * 4) & 63;
  float vals[4] = {v.x, v.y, v.z, v.w};
  float res[4];
  #pragma unroll
  for (int q = 0; q < 4; q++){
    int c = c0 + q;
    float mean = stats[c] * (1.0f/NPTS);
    float var  = stats[64+c] * (1.0f/NPTS) - mean*mean;
    float inv  = rsqrtf(var + 1e-5f);
    float y = (vals[q] - mean) * inv * g[c] + b[c];
    res[q] = fmaxf(y, 0.0f);
  }
  float4 r; r.x=res[0]; r.y=res[1]; r.z=res[2]; r.w=res[3];
  ((float4*)out)[i] = r;
}

extern "C" void kernel_launch(void* const* d_in, const int* in_sizes, int n_in,
                              void* d_out, int out_size, void* d_ws, size_t ws_size,
                              hipStream_t stream) {
  const float* feat   = (const float*)d_in[0];
  const int*   kmap   = (const int*)d_in[3];
  const float* weight = (const float*)d_in[4];
  const float* bnw    = (const float*)d_in[5];
  const float* bnb    = (const float*)d_in[6];
  float* out = (float*)d_out;

  char* ws = (char*)d_ws;
  unsigned short* featb = (unsigned short*)ws;                            // 32 MiB
  unsigned short* wpack = (unsigned short*)(ws + (size_t)NPTS*CH*2);      // 216 KiB
  float* stats = (float*)(ws + (size_t)NPTS*CH*2 + (size_t)KVOL*CH*CH*2); // 512 B

  hipMemsetAsync(d_out, 0, (size_t)out_size * sizeof(float), stream);
  hipMemsetAsync(stats, 0, 2*CH*sizeof(float), stream);

  k_conv_feat<<<NPTS*CH/4/256, 256, 0, stream>>>(feat, featb);
  k_pack_w<<<(KVOL*CH*CH + 255)/256, 256, 0, stream>>>(weight, wpack);
  k_conv<<<KVOL*1024, 256, 0, stream>>>(featb, wpack, kmap, out);
  k_reduce<<<256, 256, 0, stream>>>(out, stats);
  k_bn<<<NPTS*CH/4/256, 256, 0, stream>>>(out, stats, bnw, bnb);
}